// Round 9
// baseline (733.716 us; speedup 1.0000x reference)
//
#include <hip/hip_runtime.h>
#include <math.h>

#define D_ 128
#define H_ 160
#define W_ 160
#define NVOX (D_*H_*W_)
#define HW (H_*W_)
#define N4 (NVOX/4)

// Gaussian kernel, sigma=1, radius=2, normalized
#define K0 0.40261996f
#define K1 0.24420134f
#define K2 0.05448868f

union F4 { float4 v; float a[4]; };

__device__ __forceinline__ float4 zero4() { float4 z; z.x=z.y=z.z=z.w=0.f; return z; }

__device__ __forceinline__ float fetch_mov(const float* __restrict__ m, int d, int h, int w) {
    if ((unsigned)d >= (unsigned)D_ || (unsigned)h >= (unsigned)H_ || (unsigned)w >= (unsigned)W_) return 0.0f;
    return m[(size_t)(d*H_ + h)*W_ + w];
}

__device__ __forceinline__ float trilerp(const float* __restrict__ mov,
                                         float cd, float ch, float cw) {
    float fd = floorf(cd), fh = floorf(ch), fw = floorf(cw);
    int di = (int)fd, hi = (int)fh, wi = (int)fw;
    float td = cd - fd, th = ch - fh, tw = cw - fw;
    float c000, c001, c010, c011, c100, c101, c110, c111;
    if (di >= 0 && di < D_-1 && hi >= 0 && hi < H_-1 && wi >= 0 && wi < W_-1) {
        const float* p = mov + (size_t)di*HW + hi*W_ + wi;
        c000 = p[0];    c001 = p[1];
        c010 = p[W_];   c011 = p[W_+1];
        const float* q = p + HW;
        c100 = q[0];    c101 = q[1];
        c110 = q[W_];   c111 = q[W_+1];
    } else {
        c000 = fetch_mov(mov, di,   hi,   wi  );
        c001 = fetch_mov(mov, di,   hi,   wi+1);
        c010 = fetch_mov(mov, di,   hi+1, wi  );
        c011 = fetch_mov(mov, di,   hi+1, wi+1);
        c100 = fetch_mov(mov, di+1, hi,   wi  );
        c101 = fetch_mov(mov, di+1, hi,   wi+1);
        c110 = fetch_mov(mov, di+1, hi+1, wi  );
        c111 = fetch_mov(mov, di+1, hi+1, wi+1);
    }
    float c00 = c000 + tw*(c001 - c000);
    float c01 = c010 + tw*(c011 - c010);
    float c10 = c100 + tw*(c101 - c100);
    float c11 = c110 + tw*(c111 - c110);
    float c0 = c00 + th*(c01 - c00);
    float c1 = c10 + th*(c11 - c10);
    return c0 + td*(c1 - c0);
}

// demons force at an aligned float4 (d, gh, gw..gw+3), all inside the volume.
__device__ __forceinline__ void force_f4(const float* __restrict__ warped,
                                         const float* __restrict__ fix,
                                         const float* __restrict__ vf,
                                         int zero_vf, int d, int gh, int gw,
                                         F4& o0, F4& o1, F4& o2) {
    size_t base = (size_t)d*HW + gh*W_ + gw;
    int i4 = (int)(base >> 2);
    const float4* w4p = (const float4*)warped;
    const float4* f4p = (const float4*)fix;
    F4 c;  c.v  = w4p[i4];
    F4 fc; fc.v = f4p[i4];
    float cl = (gw > 0)     ? warped[base-1] : 0.f;
    float cr = (gw+4 < W_)  ? warped[base+4] : 0.f;
    float fl = (gw > 0)     ? fix[base-1] : 0.f;
    float fr = (gw+4 < W_)  ? fix[base+4] : 0.f;
    F4 hu;  hu.v  = (gh < H_-1) ? w4p[i4 + W_/4] : c.v;
    F4 hd;  hd.v  = (gh > 0)    ? w4p[i4 - W_/4] : c.v;
    F4 du;  du.v  = (d < D_-1)  ? w4p[i4 + HW/4] : c.v;
    F4 dn;  dn.v  = (d > 0)     ? w4p[i4 - HW/4] : c.v;
    F4 fhu; fhu.v = (gh < H_-1) ? f4p[i4 + W_/4] : fc.v;
    F4 fhd; fhd.v = (gh > 0)    ? f4p[i4 - W_/4] : fc.v;
    F4 fdu; fdu.v = (d < D_-1)  ? f4p[i4 + HW/4] : fc.v;
    F4 fdn; fdn.v = (d > 0)     ? f4p[i4 - HW/4] : fc.v;
    float hs  = (gh==0 || gh==H_-1) ? 1.f : 0.5f;
    float dsc = (d==0  || d==D_-1)  ? 1.f : 0.5f;
    if (zero_vf) {
        o0.v = zero4(); o1.v = zero4(); o2.v = zero4();
    } else {
        o0.v = ((const float4*)vf)[i4];
        o1.v = ((const float4*)vf)[i4 + N4];
        o2.v = ((const float4*)vf)[i4 + 2*N4];
    }
    float m [6] = {cl, c.a[0],  c.a[1],  c.a[2],  c.a[3],  cr};
    float fm[6] = {fl, fc.a[0], fc.a[1], fc.a[2], fc.a[3], fr};
    #pragma unroll
    for (int j = 0; j < 4; ++j) {
        int wj = gw + j;
        float wsc  = (wj == 0 || wj == W_-1) ? 1.f : 0.5f;
        float prev  = (wj == 0)    ? m[1]  : m[j];
        float next  = (wj == W_-1) ? m[4]  : m[j+2];
        float fprev = (wj == 0)    ? fm[1] : fm[j];
        float fnext = (wj == W_-1) ? fm[4] : fm[j+2];
        float G0 = dsc*(du.a[j] - dn.a[j]) + dsc*(fdu.a[j] - fdn.a[j]);
        float G1 = hs *(hu.a[j] - hd.a[j]) + hs *(fhu.a[j] - fhd.a[j]);
        float G2 = wsc*(next - prev)       + wsc*(fnext - fprev);
        float diff = c.a[j] - fc.a[j];
        float denom = G0*G0 + G1*G1 + G2*G2 + diff*diff;
        float scale = (denom > 1e-6f) ? (-diff/denom) : 0.0f;
        o0.a[j] += scale*G0;
        o1.a[j] += scale*G1;
        o2.a[j] += scale*G2;
    }
}

__device__ __forceinline__ float4 wconv(const float* rp, int k) {
    F4 a, b, cc;
    a.v  = *(const float4*)(rp + 4*k);
    b.v  = *(const float4*)(rp + 4*k + 4);
    cc.v = *(const float4*)(rp + 4*k + 8);
    float mm[12];
    #pragma unroll
    for (int j = 0; j < 4; ++j) { mm[j]=a.a[j]; mm[4+j]=b.a[j]; mm[8+j]=cc.a[j]; }
    F4 o4;
    #pragma unroll
    for (int j = 0; j < 4; ++j)
        o4.a[j] = K2*(mm[j+2]+mm[j+6]) + K1*(mm[j+3]+mm[j+5]) + K0*mm[j+4];
    return o4.v;
}

// ---------------------------------------------------------------------------
// Fused demons force + W-conv + H-conv for one (32x32 tile, plane d).
// XCD-swizzled 1D grid (3200 blocks): XCD k owns a contiguous 16-plane d-slab
// so d+-1 taps stay in the local XCD L2 (round 8: FETCH 126 -> 14 MB).
// LDS overlay: the W-conv result reuses u's storage (results held in regs
// across a barrier), halving LDS 33.3 -> 17.3 KB to lift occupancy.
// ---------------------------------------------------------------------------
__global__ __launch_bounds__(256) void force_wh_kernel(const float* __restrict__ warped,
                                                       const float* __restrict__ fix,
                                                       const float* __restrict__ vf,
                                                       float* __restrict__ tout,
                                                       int zero_vf) {
    __shared__ float u[3*36*40];      // 17.28 KB; overlaid by s1 (3*36*36) after W-conv
    const int tx = threadIdx.x;       // 0..7
    const int ty = threadIdx.y;       // 0..31
    const int tid = ty*8 + tx;
    const int bswz = (blockIdx.x & 7)*400 + (blockIdx.x >> 3);
    const int d   = bswz / 25;
    const int rem = bswz % 25;
    const int h0 = (rem / 5) * 32;
    const int w0 = (rem % 5) * 32;

    // stage force-updated slots: 360 f4 slots (36 rows x 10 cols) per channel
    for (int slot = tid; slot < 360; slot += 256) {
        int r = slot/10, c = slot%10;
        int gh = h0 - 2 + r;
        int gw = w0 - 4 + 4*c;
        F4 o0, o1, o2;
        if ((unsigned)gh < (unsigned)H_ && gw >= 0 && gw + 4 <= W_) {
            force_f4(warped, fix, vf, zero_vf, d, gh, gw, o0, o1, o2);
        } else {
            o0.v = zero4(); o1.v = zero4(); o2.v = zero4();
        }
        *(float4*)&u[(0*36 + r)*40 + 4*c] = o0.v;
        *(float4*)&u[(1*36 + r)*40 + 4*c] = o1.v;
        *(float4*)&u[(2*36 + r)*40 + 4*c] = o2.v;
    }
    __syncthreads();
    // W-conv: 864 tasks (3ch x 36 rows x 8 f4); results held in registers
    float4 res0, res1, res2, res3 = zero4();
    {
        int t0 = tid;
        res0 = wconv(&u[((t0/288)*36 + (t0%288)/8)*40], t0%8);
        int t1 = tid + 256;
        res1 = wconv(&u[((t1/288)*36 + (t1%288)/8)*40], t1%8);
        int t2 = tid + 512;
        res2 = wconv(&u[((t2/288)*36 + (t2%288)/8)*40], t2%8);
        if (tid < 96) {
            int t3 = tid + 768;
            res3 = wconv(&u[((t3/288)*36 + (t3%288)/8)*40], t3%8);
        }
    }
    __syncthreads();   // all reads of u complete
    // write W-conv results into u's storage, reinterpreted as s1[3][36][36]
    float* s1 = u;
    {
        int t0 = tid;
        *(float4*)&s1[((t0/288)*36 + (t0%288)/8)*36 + 4*(t0%8)] = res0;
        int t1 = tid + 256;
        *(float4*)&s1[((t1/288)*36 + (t1%288)/8)*36 + 4*(t1%8)] = res1;
        int t2 = tid + 512;
        *(float4*)&s1[((t2/288)*36 + (t2%288)/8)*36 + 4*(t2%8)] = res2;
        if (tid < 96) {
            int t3 = tid + 768;
            *(float4*)&s1[((t3/288)*36 + (t3%288)/8)*36 + 4*(t3%8)] = res3;
        }
    }
    __syncthreads();
    // H-conv + store
    size_t base = (size_t)d*HW + (h0+ty)*W_ + w0 + 4*tx;
    #pragma unroll
    for (int ch = 0; ch < 3; ++ch) {
        const float* sp = &s1[ch*36*36];
        float4 q0 = *(const float4*)&sp[(ty  )*36 + 4*tx];
        float4 q1 = *(const float4*)&sp[(ty+1)*36 + 4*tx];
        float4 q2 = *(const float4*)&sp[(ty+2)*36 + 4*tx];
        float4 q3 = *(const float4*)&sp[(ty+3)*36 + 4*tx];
        float4 q4 = *(const float4*)&sp[(ty+4)*36 + 4*tx];
        float4 s2;
        s2.x = K2*(q0.x+q4.x) + K1*(q1.x+q3.x) + K0*q2.x;
        s2.y = K2*(q0.y+q4.y) + K1*(q1.y+q3.y) + K0*q2.y;
        s2.z = K2*(q0.z+q4.z) + K1*(q1.z+q3.z) + K0*q2.z;
        s2.w = K2*(q0.w+q4.w) + K1*(q1.w+q3.w) + K0*q2.w;
        *(float4*)(tout + (size_t)ch*NVOX + base) = s2;
    }
}

// ---------------------------------------------------------------------------
// D-conv (streaming, taps local-XCD-L2-resident via swizzle) + trilinear warp.
// One thread per spatial float4, all 3 channels. No LDS, no barriers.
// ---------------------------------------------------------------------------
__global__ __launch_bounds__(256) void smooth_d_warp_kernel(const float* __restrict__ t,
                                                            const float* __restrict__ mov,
                                                            float* __restrict__ vf_out,
                                                            float* __restrict__ warped_out,
                                                            int do_warp) {
    const int chunk = (blockIdx.x & 7)*400 + (blockIdx.x >> 3);
    int i4 = chunk*256 + (int)threadIdx.x;
    if (i4 >= N4) return;
    int base = 4*i4;
    int w = base % W_;
    int h = (base / W_) % H_;
    int d = base / HW;
    F4 va[3];
    #pragma unroll
    for (int ch = 0; ch < 3; ++ch) {
        const float4* tp = (const float4*)(t + (size_t)ch*NVOX);
        float4 q0 = (d >= 2)    ? tp[i4 - HW/2] : zero4();
        float4 q1 = (d >= 1)    ? tp[i4 - HW/4] : zero4();
        float4 q2 = tp[i4];
        float4 q3 = (d < D_-1)  ? tp[i4 + HW/4] : zero4();
        float4 q4 = (d < D_-2)  ? tp[i4 + HW/2] : zero4();
        va[ch].a[0] = K2*(q0.x+q4.x) + K1*(q1.x+q3.x) + K0*q2.x;
        va[ch].a[1] = K2*(q0.y+q4.y) + K1*(q1.y+q3.y) + K0*q2.y;
        va[ch].a[2] = K2*(q0.z+q4.z) + K1*(q1.z+q3.z) + K0*q2.z;
        va[ch].a[3] = K2*(q0.w+q4.w) + K1*(q1.w+q3.w) + K0*q2.w;
    }
    ((float4*)vf_out)[i4]        = va[0].v;
    ((float4*)vf_out)[i4 + N4]   = va[1].v;
    ((float4*)vf_out)[i4 + 2*N4] = va[2].v;
    if (do_warp) {
        F4 r4o;
        #pragma unroll
        for (int j = 0; j < 4; ++j) {
            float cd = (float)d       + va[0].a[j];
            float ch = (float)h       + va[1].a[j];
            float cw = (float)(w + j) + va[2].a[j];
            r4o.a[j] = trilerp(mov, cd, ch, cw);
        }
        ((float4*)warped_out)[i4] = r4o.v;
    }
}

extern "C" void kernel_launch(void* const* d_in, const int* in_sizes, int n_in,
                              void* d_out, int out_size, void* d_ws, size_t ws_size,
                              hipStream_t stream) {
    const float* mov = (const float*)d_in[0];
    const float* fix = (const float*)d_in[1];
    const int ITERS = 10;

    float* ws     = (float*)d_ws;
    float* vfA    = ws;                       // 3N — the vf state
    float* tbuf   = ws + (size_t)3*NVOX;      // 3N — WH-smoothed field
    float* warped = ws + (size_t)6*NVOX;      // N

    const int nblk = 3200;   // == 5*5*128 tiles == N4/256 chunks

    for (int it = 0; it < ITERS; ++it) {
        // it==0: vf == 0 => warped == mov exactly (integer-coordinate trilerp)
        const float* wsrc = (it == 0) ? mov : warped;
        force_wh_kernel<<<dim3(nblk), dim3(8,32), 0, stream>>>(wsrc, fix, vfA, tbuf,
                                                               it == 0 ? 1 : 0);
        float* vdst = (it == ITERS-1) ? (float*)d_out : vfA;
        smooth_d_warp_kernel<<<dim3(nblk), dim3(256), 0, stream>>>(tbuf, mov, vdst, warped,
                                                                   it == ITERS-1 ? 0 : 1);
    }
}